// Round 24
// baseline (155.910 us; speedup 1.0000x reference)
//
#include <hip/hip_runtime.h>
#include <math.h>

static constexpr int NN = 40000;   // nodes
static constexpr int NE = 640000;  // edges
static constexpr int DD = 128;     // feature dim
// H=4, DK=DE=32, P=1, n_layer=0

typedef __attribute__((ext_vector_type(8))) _Float16 half8;
typedef __attribute__((ext_vector_type(2))) _Float16 half2t;
typedef __attribute__((ext_vector_type(4))) float f32x4;

// ---------- helpers ----------
__device__ __forceinline__ unsigned short f2h(float f) {
  union { _Float16 h; unsigned short s; } c; c.h = (_Float16)f; return c.s;
}
__device__ __forceinline__ half2t u2h(unsigned u) {
  union { unsigned u; half2t h; } c; c.u = u; return c.h;
}
__device__ __forceinline__ float hlo(unsigned u) {
  union { unsigned u; half2t h; } c; c.u = u; return (float)c.h.x;
}
__device__ __forceinline__ float hhi(unsigned u) {
  union { unsigned u; half2t h; } c; c.u = u; return (float)c.h.y;
}
// XOR swizzle for 256B-pitch LDS rows (row = byte>>8): flips 16B-chunk index
__device__ __forceinline__ int swz(int b) {
  return b ^ ((((b >> 8) & 7) << 4));
}
// fast gelu: z*ey/(ey+1), ey = exp(2*sqrt(2/pi)*(z + 0.044715 z^3)); max err ~2e-4
__device__ __forceinline__ float gelu_f(float z) {
  float z2 = z * z;
  float y2 = 1.5957691216057308f * z * fmaf(0.044715f, z2, 1.0f);
  float ey = __expf(y2);
  float r = __fdividef(z * ey, ey + 1.0f);
  return (z > 8.0f) ? z : r;
}

// ---------------------------------------------------------------
// Fused prologue: block-role split.
//   blocks [0,9):        weight transpose -> Wt[(mat*3+t)][c][d] fp16 (LDS-free)
//   blocks [9,5009):     LayerNorm x -> Xn fp16 (8 rows/block, float4/lane)
//   blocks [5009,7509):  edge histogram by dst + per-edge rank record
// ---------------------------------------------------------------
__global__ __launch_bounds__(256)
void prep_kernel(const float* __restrict__ Wq, const float* __restrict__ Wk,
                 const float* __restrict__ Wv, unsigned short* __restrict__ Wt,
                 const float* __restrict__ x, const float* __restrict__ gamma,
                 const float* __restrict__ beta, unsigned short* __restrict__ Xn,
                 const int* __restrict__ ei, int* __restrict__ deg,
                 int* __restrict__ rank)
{
  const int b = blockIdx.x;
  const int tid = threadIdx.x;
  if (b < 9) {
    const int mat = b / 3, t = b % 3;
    const float* W = (mat == 0) ? Wq : (mat == 1) ? Wk : Wv;
#pragma unroll
    for (int i = 0; i < 8; ++i) {
      int idx = i * 256 + tid;          // 0..2047
      int c = idx >> 4, ch = idx & 15;
      int h = c >> 5, k = c & 31;
      union { unsigned short s[8]; uint4 v; } u;
#pragma unroll
      for (int j = 0; j < 8; ++j) {
        int d = ch * 8 + j;
        u.s[j] = f2h(W[(size_t)((h * 3 + t) * 128 + d) * 32 + k]);
      }
      *(uint4*)&Wt[(size_t)b * 16384 + c * 128 + ch * 8] = u.v;
    }
  } else if (b < 5009) {
    const int r = (b - 9) * 8 + (tid >> 5);   // 8 rows/block, 32 lanes/row
    const int l32 = tid & 31;
    float4 v = *(const float4*)(x + (size_t)r * DD + l32 * 4);
    float s  = v.x + v.y + v.z + v.w;
    float ss = v.x * v.x + v.y * v.y + v.z * v.z + v.w * v.w;
#pragma unroll
    for (int off = 1; off < 32; off <<= 1) { s += __shfl_xor(s, off); ss += __shfl_xor(ss, off); }
    float mu = s * (1.f / 128.f);
    float rs = rsqrtf(ss * (1.f / 128.f) - mu * mu + 1e-5f);
    float4 g = *(const float4*)(gamma + l32 * 4);
    float4 bb = *(const float4*)(beta + l32 * 4);
    ushort4 o;
    o.x = f2h((v.x - mu) * rs * g.x + bb.x);
    o.y = f2h((v.y - mu) * rs * g.y + bb.y);
    o.z = f2h((v.z - mu) * rs * g.z + bb.z);
    o.w = f2h((v.w - mu) * rs * g.w + bb.w);
    *(ushort4*)(Xn + (size_t)r * DD + l32 * 4) = o;
  } else {
    int e = (b - 5009) * 256 + tid;
    rank[e] = atomicAdd(&deg[ei[NE + e]], 1);
  }
}

// ---------------------------------------------------------------
// Single-kernel scan: block b sums deg[0..b*256) directly (L2-resident)
// for its offset, plus wave-scan of its own 256-chunk.
// ---------------------------------------------------------------
__global__ __launch_bounds__(256)
void scan_kernel(const int* __restrict__ deg, int* __restrict__ base)
{
  const int b = blockIdx.x, tid = threadIdx.x;
  __shared__ int ws4[4];
  __shared__ int wsum[4];
  // prefix over preceding chunks
  int pre = 0;
  for (int i = tid; i < b * 256; i += 256) pre += deg[i];
#pragma unroll
  for (int off = 1; off < 64; off <<= 1) pre += __shfl_xor(pre, off);
  if ((tid & 63) == 0) ws4[tid >> 6] = pre;
  __syncthreads();
  int boff = ws4[0] + ws4[1] + ws4[2] + ws4[3];
  // local scan of own chunk
  int i = b * 256 + tid;
  int v = (i < NN) ? deg[i] : 0;
  int xv = v;
#pragma unroll
  for (int off = 1; off < 64; off <<= 1) {
    int y = __shfl_up(xv, off);
    if ((tid & 63) >= off) xv += y;
  }
  if ((tid & 63) == 63) wsum[tid >> 6] = xv;
  __syncthreads();
  int add = 0;
  if (tid >= 64)  add += wsum[0];
  if (tid >= 128) add += wsum[1];
  if (tid >= 192) add += wsum[2];
  xv += add;
  if (i < NN) base[i] = boff + xv - v;   // global exclusive
  if (b == 0 && tid == 0) base[NN] = NE;
}

// ---------------------------------------------------------------
// Fused QKV projection + edge scatter (R20-measured-best structure, fp16).
//   blocks [0,5625):   QKV MFMA 64-row x 128-col tile: combo = b%9,
//                      n0 = (b/9)*64. A-fragments direct global->reg
//                      (coalesced); B (Wt slab) LDS-staged; epilogue
//                      repack reuses wt (compile-time ct indices only).
//   blocks [5625,8125): scatter edges into CSR slots (no atomics).
// Q -> Qo [t*NN+n][128]; K/V -> KVo interleaved [t*NN+n][256].
// ---------------------------------------------------------------
__global__ __launch_bounds__(256)
void qkvs_kernel(const unsigned short* __restrict__ Xn,
                 const float* __restrict__ bq, const float* __restrict__ bk,
                 const float* __restrict__ bv,
                 const unsigned short* __restrict__ Wt,
                 unsigned short* __restrict__ Qo, unsigned short* __restrict__ KVo,
                 const int* __restrict__ ei, const float* __restrict__ ev,
                 const float* __restrict__ m1, const float* __restrict__ m2,
                 const int* __restrict__ base, const int* __restrict__ rank,
                 int2* __restrict__ esl)
{
  __shared__ unsigned char wt[32768];  // 128 c-rows x 256B (swizzled); reused for repack
  const int b = blockIdx.x;
  const int tid = threadIdx.x;
  if (b >= 5625) {
    // ---- scatter role: slot = base[dst] + rank[e]; esl = {ro, decay} ----
    int e = (b - 5625) * 256 + tid;
    int src = ei[e];
    int dst = ei[NE + e];
    int tn = (m1[e] > 0.5f) ? NN : ((m2[e] > 0.5f) ? 2 * NN : 0);
    float av = fabsf(ev[e]);
    float decay = exp2f(-0.15200309344504995f * av);      // 0.9^|v|
    int slot = base[dst] + rank[e];
    int2 v; v.x = tn + src; v.y = __float_as_int(decay);
    esl[slot] = v;
    return;
  }

  const int lane = tid & 63;
  const int w = tid >> 6;
  const int l15 = lane & 15, kh = lane >> 4;
  const int combo = b % 9;
  const int n0 = (b / 9) * 64;
  const int mat = combo / 3, t = combo % 3;
  const float* B = (mat == 0) ? bq : (mat == 1) ? bk : bv;
  unsigned short* O; int ostride;
  if (mat == 0)      { O = Qo;        ostride = 128; }
  else if (mat == 1) { O = KVo;       ostride = 256; }
  else               { O = KVo + 128; ostride = 256; }

  // ---- A-fragments direct to registers (issue first, overlap staging) ----
  const unsigned short* xp = Xn + (size_t)(n0 + w * 16 + l15) * 128 + kh * 8;
  half8 a0 = *(const half8*)(xp);
  half8 a1 = *(const half8*)(xp + 32);
  half8 a2 = *(const half8*)(xp + 64);
  half8 a3 = *(const half8*)(xp + 96);

  // ---- stage Wt slab (32KB) ----
#pragma unroll
  for (int i = 0; i < 8; ++i) {
    int idx = i * 256 + tid;
    int rr = idx >> 4, ch = idx & 15;
    uint4 d4 = *(const uint4*)(Wt + (size_t)combo * 16384 + rr * 128 + ch * 8);
    *(uint4*)(wt + swz(rr * 256 + ch * 16)) = d4;
  }

  // ---- init acc with bias ----
  f32x4 acc[8];
#pragma unroll
  for (int ct = 0; ct < 8; ++ct) {
    int cc = ct * 16 + l15;
    float bb = B[((cc >> 5) * 3 + t) * 32 + (cc & 31)];
    f32x4 bi = {bb, bb, bb, bb};
    acc[ct] = bi;
  }
  __syncthreads();

  // ---- MFMA: 8 col-tiles x 4 k-steps (A from regs, B from LDS, fp16) ----
#pragma unroll
  for (int ct = 0; ct < 8; ++ct) {
    half8 bf0 = *(const half8*)(wt + swz((ct * 16 + l15) * 256 + 0 * 64 + kh * 16));
    half8 bf1 = *(const half8*)(wt + swz((ct * 16 + l15) * 256 + 1 * 64 + kh * 16));
    half8 bf2 = *(const half8*)(wt + swz((ct * 16 + l15) * 256 + 2 * 64 + kh * 16));
    half8 bf3 = *(const half8*)(wt + swz((ct * 16 + l15) * 256 + 3 * 64 + kh * 16));
    acc[ct] = __builtin_amdgcn_mfma_f32_16x16x32_f16(a0, bf0, acc[ct], 0, 0, 0);
    acc[ct] = __builtin_amdgcn_mfma_f32_16x16x32_f16(a1, bf1, acc[ct], 0, 0, 0);
    acc[ct] = __builtin_amdgcn_mfma_f32_16x16x32_f16(a2, bf2, acc[ct], 0, 0, 0);
    acc[ct] = __builtin_amdgcn_mfma_f32_16x16x32_f16(a3, bf3, acc[ct], 0, 0, 0);
  }
  __syncthreads();   // all waves done reading wt

  // ---- epilogue: repack into wt[0:16K) with compile-time ct order ----
#pragma unroll
  for (int ct = 0; ct < 8; ++ct)
#pragma unroll
    for (int rg = 0; rg < 4; ++rg) {
      int rr = w * 16 + kh * 4 + rg;
      int cc = ct * 16 + l15;
      *(unsigned short*)(wt + swz(rr * 256 + cc * 2)) = f2h(acc[ct][rg]);
    }
  __syncthreads();
#pragma unroll
  for (int i = 0; i < 4; ++i) {
    int idx = i * 256 + tid;
    int rr = idx >> 4, ch = idx & 15;
    uint4 d4 = *(const uint4*)(wt + swz(rr * 256 + ch * 16));
    *(uint4*)(O + ((size_t)t * NN + n0 + rr) * ostride + ch * 8) = d4;
  }
}

// ---------------------------------------------------------------
// Fused per-node attention, wave-synchronous, unified 16-lane-per-edge.
//   - esl.x is the pre-scaled KV row index ro: address = KV + (ro<<8).
//   - Q fragments for all 3 t preloaded in registers; per-edge reg-select.
//   - QK dot via v_dot2_f32_f16 (fdot2): 4 insts/fragment vs ~32 bf16 ops.
//   - quad reduce (shfl_xor 1,2 = DPP) completes each head's dot.
//   - epilogue on ALL 64 lanes (2 comps each) with fast-gelu.
// Branchless (clamped slot); padding edges carry weight 0.
// Softmax without max-shift (scores bounded; global shift cancels ~1e-10).
// ---------------------------------------------------------------
__global__ __launch_bounds__(256)
void agg_kernel(const float* __restrict__ x,
                const unsigned short* __restrict__ Q,
                const unsigned short* __restrict__ KV,
                const int2* __restrict__ esl, const int* __restrict__ base,
                float* __restrict__ out)
{
  const int l = threadIdx.x & 63;
  const int n = blockIdx.x * 4 + (threadIdx.x >> 6);
  const int b0 = base[n], b1 = base[n + 1];
  const int g = l >> 4, l15 = l & 15;      // group, lane-in-group
  float acc[8] = {0.f, 0.f, 0.f, 0.f, 0.f, 0.f, 0.f, 0.f};
  float den = 0.f;

  // preload this lane's 16B Q fragment for each t
  const uint4 q0 = *(const uint4*)(Q + ((size_t)0 * NN + n) * DD + l15 * 8);
  const uint4 q1 = *(const uint4*)(Q + ((size_t)1 * NN + n) * DD + l15 * 8);
  const uint4 q2 = *(const uint4*)(Q + ((size_t)2 * NN + n) * DD + l15 * 8);

  const int last = b1 - 1;
  for (int cs = b0; cs < b1; cs += 8) {
    int jA = cs + g;
    int jB = cs + 4 + g;
    bool actA = (jA < b1), actB = (jB < b1);
    int2 ecA = esl[actA ? jA : last];
    int2 ecB = esl[actB ? jB : last];
    const int roA = ecA.x, roB = ecB.x;
    const unsigned short* krA = KV + ((size_t)roA << 8);
    const unsigned short* krB = KV + ((size_t)roB << 8);
    uint4 kA = *(const uint4*)(krA + l15 * 8);
    uint4 vA = *(const uint4*)(krA + 128 + l15 * 8);
    uint4 kB = *(const uint4*)(krB + l15 * 8);
    uint4 vB = *(const uint4*)(krB + 128 + l15 * 8);
    uint4 qA = (roA < NN) ? q0 : ((roA < 2 * NN) ? q1 : q2);
    uint4 qB = (roB < NN) ? q0 : ((roB < 2 * NN) ? q1 : q2);

    float dA = __builtin_amdgcn_fdot2(u2h(kA.x), u2h(qA.x), 0.f, false);
    dA = __builtin_amdgcn_fdot2(u2h(kA.y), u2h(qA.y), dA, false);
    dA = __builtin_amdgcn_fdot2(u2h(kA.z), u2h(qA.z), dA, false);
    dA = __builtin_amdgcn_fdot2(u2h(kA.w), u2h(qA.w), dA, false);
    float dB = __builtin_amdgcn_fdot2(u2h(kB.x), u2h(qB.x), 0.f, false);
    dB = __builtin_amdgcn_fdot2(u2h(kB.y), u2h(qB.y), dB, false);
    dB = __builtin_amdgcn_fdot2(u2h(kB.z), u2h(qB.z), dB, false);
    dB = __builtin_amdgcn_fdot2(u2h(kB.w), u2h(qB.w), dB, false);
    // quad-local reduce: full head-dot in every lane (DPP-cheap)
    dA += __shfl_xor(dA, 1);  dA += __shfl_xor(dA, 2);
    dB += __shfl_xor(dB, 1);  dB += __shfl_xor(dB, 2);
    float aA = __expf(dA * 0.17677669529663687f * __int_as_float(ecA.y));
    float aB = __expf(dB * 0.17677669529663687f * __int_as_float(ecB.y));
    aA = actA ? aA : 0.f;
    aB = actB ? aB : 0.f;
    den += aA + aB;
    acc[0] += aA * hlo(vA.x) + aB * hlo(vB.x);
    acc[1] += aA * hhi(vA.x) + aB * hhi(vB.x);
    acc[2] += aA * hlo(vA.y) + aB * hlo(vB.y);
    acc[3] += aA * hhi(vA.y) + aB * hhi(vB.y);
    acc[4] += aA * hlo(vA.z) + aB * hlo(vB.z);
    acc[5] += aA * hhi(vA.z) + aB * hhi(vB.z);
    acc[6] += aA * hlo(vA.w) + aB * hlo(vB.w);
    acc[7] += aA * hhi(vA.w) + aB * hhi(vB.w);
  }

  // cross-group combine: after this ALL lanes hold the full sums
#pragma unroll
  for (int k2 = 0; k2 < 8; ++k2) {
    acc[k2] += __shfl_xor(acc[k2], 16);
    acc[k2] += __shfl_xor(acc[k2], 32);
  }
  den += __shfl_xor(den, 16);
  den += __shfl_xor(den, 32);
  float rdh = __fdividef(1.0f, den + 1e-16f);   // lane's den IS its head's denom
  // each lane handles 2 comps: c0 = l15*8 + 2g (same head l15>>2)
  const int c0 = l15 * 8 + g * 2;
  float2 xr = *(const float2*)(x + (size_t)n * DD + c0);
  float z0 = acc[g * 2] * rdh;
  float z1 = acc[g * 2 + 1] * rdh;
  float2 o;
  o.x = xr.x + gelu_f(z0);
  o.y = xr.y + gelu_f(z1);
  *(float2*)(out + (size_t)n * DD + c0) = o;
}

// ---------------------------------------------------------------
extern "C" void kernel_launch(void* const* d_in, const int* in_sizes, int n_in,
                              void* d_out, int out_size, void* d_ws, size_t ws_size,
                              hipStream_t stream)
{
  const float* x     = (const float*)d_in[0];
  const int*   ei    = (const int*)d_in[1];
  const float* ev    = (const float*)d_in[2];
  const float* m1    = (const float*)d_in[5];  // diff_time_same_var -> t=1
  const float* m2    = (const float*)d_in[6];  // diff_time_diff_var -> t=2
  const float* gamma = (const float*)d_in[8];
  const float* beta  = (const float*)d_in[9];
  const float* Wq    = (const float*)d_in[10];
  const float* bq    = (const float*)d_in[11];
  const float* Wk    = (const float*)d_in[12];
  const float* bk    = (const float*)d_in[13];
  const float* Wv    = (const float*)d_in[14];
  const float* bv    = (const float*)d_in[15];
  float* out = (float*)d_out;

  // ---- workspace layout ----
  unsigned short* Q  = (unsigned short*)d_ws;        // 3*NN*128 fp16
  unsigned short* KV = Q  + (size_t)3 * NN * DD;     // 3*NN*256 fp16 (K|V interleaved)
  unsigned short* Xn = KV + (size_t)3 * NN * 256;    // NN*128 fp16
  unsigned short* Wt = Xn + (size_t)NN * DD;         // 9*16384 fp16
  int2*  esl  = (int2*)(Wt + 9 * 16384);             // NE int2 (8B-aligned)
  int*   rank = (int*)(esl + NE);                    // NE
  int*   deg  = rank + NE;                           // NN
  int*   base = deg + NN;                            // NN+1

  hipMemsetAsync(deg, 0, (size_t)NN * sizeof(int), stream);  // deg only

  prep_kernel<<<7509, 256, 0, stream>>>(Wq, Wk, Wv, Wt, x, gamma, beta, Xn, ei, deg, rank);
  scan_kernel<<<157, 256, 0, stream>>>(deg, base);
  qkvs_kernel<<<5625 + 2500, 256, 0, stream>>>(Xn, bq, bk, bv, Wt, Q, KV,
                                               ei, ev, m1, m2, base, rank, esl);
  agg_kernel<<<NN / 4, 256, 0, stream>>>(x, Q, KV, esl, base, out);
}

// Round 25
// 136.887 us; speedup vs baseline: 1.1390x; 1.1390x over previous
//
#include <hip/hip_runtime.h>
#include <math.h>

static constexpr int NN = 40000;   // nodes
static constexpr int NE = 640000;  // edges
static constexpr int DD = 128;     // feature dim
// H=4, DK=DE=32, P=1, n_layer=0

typedef __attribute__((ext_vector_type(8))) short short8;
typedef __attribute__((ext_vector_type(4))) float f32x4;

// ---------- helpers ----------
__device__ __forceinline__ unsigned short f2b(float f) {
  unsigned u = __float_as_uint(f);
  unsigned r = (u + 0x7FFFu + ((u >> 16) & 1u)) >> 16;  // RNE
  return (unsigned short)r;
}
// XOR swizzle for 256B-pitch LDS rows (row = byte>>8): flips 16B-chunk index
__device__ __forceinline__ int swz(int b) {
  return b ^ ((((b >> 8) & 7) << 4));
}
__device__ __forceinline__ float pdot(unsigned a, unsigned b) {
  float al = __uint_as_float(a << 16), ah = __uint_as_float(a & 0xFFFF0000u);
  float bl = __uint_as_float(b << 16), bh = __uint_as_float(b & 0xFFFF0000u);
  return al * bl + ah * bh;
}
__device__ __forceinline__ float blo(unsigned a) { return __uint_as_float(a << 16); }
__device__ __forceinline__ float bhi(unsigned a) { return __uint_as_float(a & 0xFFFF0000u); }
// fast gelu: z*ey/(ey+1), ey = exp(2*sqrt(2/pi)*(z + 0.044715 z^3)); max err ~2e-4
__device__ __forceinline__ float gelu_f(float z) {
  float z2 = z * z;
  float y2 = 1.5957691216057308f * z * fmaf(0.044715f, z2, 1.0f);
  float ey = __expf(y2);
  float r = __fdividef(z * ey, ey + 1.0f);
  return (z > 8.0f) ? z : r;
}

// ---------------------------------------------------------------
// Fused prologue: block-role split.
//   blocks [0,9):        weight transpose -> Wt[(mat*3+t)][c][d] bf16 (LDS-free)
//   blocks [9,5009):     LayerNorm x -> Xn bf16 (8 rows/block, float4/lane)
//   blocks [5009,7509):  edge histogram by dst + per-edge rank record
// ---------------------------------------------------------------
__global__ __launch_bounds__(256)
void prep_kernel(const float* __restrict__ Wq, const float* __restrict__ Wk,
                 const float* __restrict__ Wv, unsigned short* __restrict__ Wt,
                 const float* __restrict__ x, const float* __restrict__ gamma,
                 const float* __restrict__ beta, unsigned short* __restrict__ Xn,
                 const int* __restrict__ ei, int* __restrict__ deg,
                 int* __restrict__ rank)
{
  const int b = blockIdx.x;
  const int tid = threadIdx.x;
  if (b < 9) {
    const int mat = b / 3, t = b % 3;
    const float* W = (mat == 0) ? Wq : (mat == 1) ? Wk : Wv;
#pragma unroll
    for (int i = 0; i < 8; ++i) {
      int idx = i * 256 + tid;          // 0..2047
      int c = idx >> 4, ch = idx & 15;
      int h = c >> 5, k = c & 31;
      union { unsigned short s[8]; uint4 v; } u;
#pragma unroll
      for (int j = 0; j < 8; ++j) {
        int d = ch * 8 + j;
        u.s[j] = f2b(W[(size_t)((h * 3 + t) * 128 + d) * 32 + k]);
      }
      *(uint4*)&Wt[(size_t)b * 16384 + c * 128 + ch * 8] = u.v;
    }
  } else if (b < 5009) {
    const int r = (b - 9) * 8 + (tid >> 5);   // 8 rows/block, 32 lanes/row
    const int l32 = tid & 31;
    float4 v = *(const float4*)(x + (size_t)r * DD + l32 * 4);
    float s  = v.x + v.y + v.z + v.w;
    float ss = v.x * v.x + v.y * v.y + v.z * v.z + v.w * v.w;
#pragma unroll
    for (int off = 1; off < 32; off <<= 1) { s += __shfl_xor(s, off); ss += __shfl_xor(ss, off); }
    float mu = s * (1.f / 128.f);
    float rs = rsqrtf(ss * (1.f / 128.f) - mu * mu + 1e-5f);
    float4 g = *(const float4*)(gamma + l32 * 4);
    float4 bb = *(const float4*)(beta + l32 * 4);
    ushort4 o;
    o.x = f2b((v.x - mu) * rs * g.x + bb.x);
    o.y = f2b((v.y - mu) * rs * g.y + bb.y);
    o.z = f2b((v.z - mu) * rs * g.z + bb.z);
    o.w = f2b((v.w - mu) * rs * g.w + bb.w);
    *(ushort4*)(Xn + (size_t)r * DD + l32 * 4) = o;
  } else {
    int e = (b - 5009) * 256 + tid;
    rank[e] = atomicAdd(&deg[ei[NE + e]], 1);
  }
}

// ---- two-level scan: part + (mid+add fused) ----
__global__ __launch_bounds__(256)
void scan_part(const int* __restrict__ deg, int* __restrict__ base, int* __restrict__ bsum)
{
  const int b = blockIdx.x, tid = threadIdx.x;
  int i = b * 256 + tid;
  int v = (i < NN) ? deg[i] : 0;
  int xv = v;
#pragma unroll
  for (int off = 1; off < 64; off <<= 1) {
    int y = __shfl_up(xv, off);
    if ((tid & 63) >= off) xv += y;
  }
  __shared__ int wsum[4];
  if ((tid & 63) == 63) wsum[tid >> 6] = xv;
  __syncthreads();
  int add = 0;
  if (tid >= 64)  add += wsum[0];
  if (tid >= 128) add += wsum[1];
  if (tid >= 192) add += wsum[2];
  xv += add;
  if (i < NN) base[i] = xv - v;   // local exclusive
  if (tid == 255) bsum[b] = xv;
}

// Each block sums bsum[i < blockIdx.x] (157 values) and adds to its chunk.
__global__ __launch_bounds__(256)
void scan_fin(int* __restrict__ base, const int* __restrict__ bsum)
{
  const int b = blockIdx.x, tid = threadIdx.x;
  int v = (tid < b && tid < 157) ? bsum[tid] : 0;
#pragma unroll
  for (int off = 1; off < 64; off <<= 1) v += __shfl_xor(v, off);
  __shared__ int ws4[4];
  if ((tid & 63) == 0) ws4[tid >> 6] = v;
  __syncthreads();
  int boff = ws4[0] + ws4[1] + ws4[2] + ws4[3];
  int i = b * 256 + tid;
  if (i < NN) base[i] += boff;
  if (b == 0 && tid == 0) base[NN] = NE;
}

// ---------------------------------------------------------------
// Fused QKV projection + edge scatter.
//   blocks [0,5625):   QKV MFMA tile: combo = b%9 (9 consecutive blocks
//                      share one Xn tile via L2), n0 = (b/9)*64.
//     A-fragments: DIRECT global->reg (16 rows x 64B segments — coalesced).
//     B (Wt slab): LDS-staged (fixes its 256B-strided per-lane pattern).
//     Epilogue: COMPILE-TIME ct indices only (runtime-indexed acc[]
//     goes to scratch — rule #20).
//   blocks [5625,8125): scatter edges into CSR slots (no atomics).
// Q -> Qo [t*NN+n][128]; K/V -> KVo interleaved [t*NN+n][256].
// ---------------------------------------------------------------
__global__ __launch_bounds__(256)
void qkvs_kernel(const unsigned short* __restrict__ Xn,
                 const float* __restrict__ bq, const float* __restrict__ bk,
                 const float* __restrict__ bv,
                 const unsigned short* __restrict__ Wt,
                 unsigned short* __restrict__ Qo, unsigned short* __restrict__ KVo,
                 const int* __restrict__ ei, const float* __restrict__ ev,
                 const float* __restrict__ m1, const float* __restrict__ m2,
                 const int* __restrict__ base, const int* __restrict__ rank,
                 int2* __restrict__ esl)
{
  __shared__ unsigned char wt[32768];  // 128 c-rows x 256B (swizzled); reused for repack
  const int b = blockIdx.x;
  const int tid = threadIdx.x;
  if (b >= 5625) {
    // ---- scatter role: slot = base[dst] + rank[e]; esl = {ro, decay} ----
    int e = (b - 5625) * 256 + tid;
    int src = ei[e];
    int dst = ei[NE + e];
    int tn = (m1[e] > 0.5f) ? NN : ((m2[e] > 0.5f) ? 2 * NN : 0);
    float av = fabsf(ev[e]);
    float decay = exp2f(-0.15200309344504995f * av);      // 0.9^|v|
    int slot = base[dst] + rank[e];
    int2 v; v.x = tn + src; v.y = __float_as_int(decay);
    esl[slot] = v;
    return;
  }

  const int lane = tid & 63;
  const int w = tid >> 6;
  const int l15 = lane & 15, kh = lane >> 4;
  const int combo = b % 9;
  const int n0 = (b / 9) * 64;
  const int mat = combo / 3, t = combo % 3;
  const float* B = (mat == 0) ? bq : (mat == 1) ? bk : bv;
  unsigned short* O; int ostride;
  if (mat == 0)      { O = Qo;        ostride = 128; }
  else if (mat == 1) { O = KVo;       ostride = 256; }
  else               { O = KVo + 128; ostride = 256; }

  // ---- A-fragments direct to registers (issue first, overlap staging) ----
  const unsigned short* xp = Xn + (size_t)(n0 + w * 16 + l15) * 128 + kh * 8;
  short8 a0 = *(const short8*)(xp);
  short8 a1 = *(const short8*)(xp + 32);
  short8 a2 = *(const short8*)(xp + 64);
  short8 a3 = *(const short8*)(xp + 96);

  // ---- stage Wt slab (32KB) ----
#pragma unroll
  for (int i = 0; i < 8; ++i) {
    int idx = i * 256 + tid;
    int rr = idx >> 4, ch = idx & 15;
    uint4 d4 = *(const uint4*)(Wt + (size_t)combo * 16384 + rr * 128 + ch * 8);
    *(uint4*)(wt + swz(rr * 256 + ch * 16)) = d4;
  }

  // ---- init acc with bias ----
  f32x4 acc[8];
#pragma unroll
  for (int ct = 0; ct < 8; ++ct) {
    int cc = ct * 16 + l15;
    float bb = B[((cc >> 5) * 3 + t) * 32 + (cc & 31)];
    f32x4 bi = {bb, bb, bb, bb};
    acc[ct] = bi;
  }
  __syncthreads();

  // ---- MFMA: 8 col-tiles x 4 k-steps (A from regs, B from LDS) ----
#pragma unroll
  for (int ct = 0; ct < 8; ++ct) {
    short8 bf0 = *(const short8*)(wt + swz((ct * 16 + l15) * 256 + 0 * 64 + kh * 16));
    short8 bf1 = *(const short8*)(wt + swz((ct * 16 + l15) * 256 + 1 * 64 + kh * 16));
    short8 bf2 = *(const short8*)(wt + swz((ct * 16 + l15) * 256 + 2 * 64 + kh * 16));
    short8 bf3 = *(const short8*)(wt + swz((ct * 16 + l15) * 256 + 3 * 64 + kh * 16));
    acc[ct] = __builtin_amdgcn_mfma_f32_16x16x32_bf16(a0, bf0, acc[ct], 0, 0, 0);
    acc[ct] = __builtin_amdgcn_mfma_f32_16x16x32_bf16(a1, bf1, acc[ct], 0, 0, 0);
    acc[ct] = __builtin_amdgcn_mfma_f32_16x16x32_bf16(a2, bf2, acc[ct], 0, 0, 0);
    acc[ct] = __builtin_amdgcn_mfma_f32_16x16x32_bf16(a3, bf3, acc[ct], 0, 0, 0);
  }
  __syncthreads();   // all waves done reading wt

  // ---- epilogue: repack into wt[0:16K) with compile-time ct order ----
#pragma unroll
  for (int ct = 0; ct < 8; ++ct)
#pragma unroll
    for (int rg = 0; rg < 4; ++rg) {
      int rr = w * 16 + kh * 4 + rg;
      int cc = ct * 16 + l15;
      *(unsigned short*)(wt + swz(rr * 256 + cc * 2)) = f2b(acc[ct][rg]);
    }
  __syncthreads();
#pragma unroll
  for (int i = 0; i < 4; ++i) {
    int idx = i * 256 + tid;
    int rr = idx >> 4, ch = idx & 15;
    uint4 d4 = *(const uint4*)(wt + swz(rr * 256 + ch * 16));
    *(uint4*)(O + ((size_t)t * NN + n0 + rr) * ostride + ch * 8) = d4;
  }
}

// ---------------------------------------------------------------
// Fused per-node attention, wave-synchronous, unified 16-lane-per-edge.
//   - esl.x is the pre-scaled KV row index ro: address = KV + (ro<<8).
//   - Q fragments for all 3 t preloaded in registers; per-edge reg-select.
//   - QK dot: 4-pair partial + quad reduce (shfl_xor 1,2 = DPP).
//   - epilogue on ALL 64 lanes (2 comps each) with fast-gelu.
// Branchless (clamped slot); padding edges carry weight 0.
// Softmax without max-shift (scores bounded; global shift cancels ~1e-10).
// ---------------------------------------------------------------
__global__ __launch_bounds__(256)
void agg_kernel(const float* __restrict__ x,
                const unsigned short* __restrict__ Q,
                const unsigned short* __restrict__ KV,
                const int2* __restrict__ esl, const int* __restrict__ base,
                float* __restrict__ out)
{
  const int l = threadIdx.x & 63;
  const int n = blockIdx.x * 4 + (threadIdx.x >> 6);
  const int b0 = base[n], b1 = base[n + 1];
  const int g = l >> 4, l15 = l & 15;      // group, lane-in-group
  float acc[8] = {0.f, 0.f, 0.f, 0.f, 0.f, 0.f, 0.f, 0.f};
  float den = 0.f;

  // preload this lane's 16B Q fragment for each t
  const uint4 q0 = *(const uint4*)(Q + ((size_t)0 * NN + n) * DD + l15 * 8);
  const uint4 q1 = *(const uint4*)(Q + ((size_t)1 * NN + n) * DD + l15 * 8);
  const uint4 q2 = *(const uint4*)(Q + ((size_t)2 * NN + n) * DD + l15 * 8);

  const int last = b1 - 1;
  for (int cs = b0; cs < b1; cs += 8) {
    int jA = cs + g;
    int jB = cs + 4 + g;
    bool actA = (jA < b1), actB = (jB < b1);
    int2 ecA = esl[actA ? jA : last];
    int2 ecB = esl[actB ? jB : last];
    const int roA = ecA.x, roB = ecB.x;
    const unsigned short* krA = KV + ((size_t)roA << 8);
    const unsigned short* krB = KV + ((size_t)roB << 8);
    uint4 kA = *(const uint4*)(krA + l15 * 8);
    uint4 vA = *(const uint4*)(krA + 128 + l15 * 8);
    uint4 kB = *(const uint4*)(krB + l15 * 8);
    uint4 vB = *(const uint4*)(krB + 128 + l15 * 8);
    uint4 qA = (roA < NN) ? q0 : ((roA < 2 * NN) ? q1 : q2);
    uint4 qB = (roB < NN) ? q0 : ((roB < 2 * NN) ? q1 : q2);

    float dA = pdot(kA.x, qA.x) + pdot(kA.y, qA.y) + pdot(kA.z, qA.z) + pdot(kA.w, qA.w);
    float dB = pdot(kB.x, qB.x) + pdot(kB.y, qB.y) + pdot(kB.z, qB.z) + pdot(kB.w, qB.w);
    // quad-local reduce: full head-dot in every lane (DPP-cheap)
    dA += __shfl_xor(dA, 1);  dA += __shfl_xor(dA, 2);
    dB += __shfl_xor(dB, 1);  dB += __shfl_xor(dB, 2);
    float aA = __expf(dA * 0.17677669529663687f * __int_as_float(ecA.y));
    float aB = __expf(dB * 0.17677669529663687f * __int_as_float(ecB.y));
    aA = actA ? aA : 0.f;
    aB = actB ? aB : 0.f;
    den += aA + aB;
    acc[0] += aA * blo(vA.x) + aB * blo(vB.x);
    acc[1] += aA * bhi(vA.x) + aB * bhi(vB.x);
    acc[2] += aA * blo(vA.y) + aB * blo(vB.y);
    acc[3] += aA * bhi(vA.y) + aB * bhi(vB.y);
    acc[4] += aA * blo(vA.z) + aB * blo(vB.z);
    acc[5] += aA * bhi(vA.z) + aB * bhi(vB.z);
    acc[6] += aA * blo(vA.w) + aB * blo(vB.w);
    acc[7] += aA * bhi(vA.w) + aB * bhi(vB.w);
  }

  // cross-group combine: after this ALL lanes hold the full sums
#pragma unroll
  for (int k2 = 0; k2 < 8; ++k2) {
    acc[k2] += __shfl_xor(acc[k2], 16);
    acc[k2] += __shfl_xor(acc[k2], 32);
  }
  den += __shfl_xor(den, 16);
  den += __shfl_xor(den, 32);
  float rdh = __fdividef(1.0f, den + 1e-16f);   // lane's den IS its head's denom
  // each lane handles 2 comps: c0 = l15*8 + 2g (same head l15>>2)
  const int c0 = l15 * 8 + g * 2;
  float2 xr = *(const float2*)(x + (size_t)n * DD + c0);
  float z0 = acc[g * 2] * rdh;
  float z1 = acc[g * 2 + 1] * rdh;
  float2 o;
  o.x = xr.x + gelu_f(z0);
  o.y = xr.y + gelu_f(z1);
  *(float2*)(out + (size_t)n * DD + c0) = o;
}

// ---------------------------------------------------------------
extern "C" void kernel_launch(void* const* d_in, const int* in_sizes, int n_in,
                              void* d_out, int out_size, void* d_ws, size_t ws_size,
                              hipStream_t stream)
{
  const float* x     = (const float*)d_in[0];
  const int*   ei    = (const int*)d_in[1];
  const float* ev    = (const float*)d_in[2];
  const float* m1    = (const float*)d_in[5];  // diff_time_same_var -> t=1
  const float* m2    = (const float*)d_in[6];  // diff_time_diff_var -> t=2
  const float* gamma = (const float*)d_in[8];
  const float* beta  = (const float*)d_in[9];
  const float* Wq    = (const float*)d_in[10];
  const float* bq    = (const float*)d_in[11];
  const float* Wk    = (const float*)d_in[12];
  const float* bk    = (const float*)d_in[13];
  const float* Wv    = (const float*)d_in[14];
  const float* bv    = (const float*)d_in[15];
  float* out = (float*)d_out;

  // ---- workspace layout ----
  unsigned short* Q  = (unsigned short*)d_ws;        // 3*NN*128 bf16
  unsigned short* KV = Q  + (size_t)3 * NN * DD;     // 3*NN*256 bf16 (K|V interleaved)
  unsigned short* Xn = KV + (size_t)3 * NN * 256;    // NN*128 bf16
  unsigned short* Wt = Xn + (size_t)NN * DD;         // 9*16384 bf16
  int2*  esl  = (int2*)(Wt + 9 * 16384);             // NE int2 (8B-aligned)
  int*   rank = (int*)(esl + NE);                    // NE
  int*   deg  = rank + NE;                           // NN
  int*   base = deg + NN;                            // NN+1
  int*   bsum = base + NN + 1;                       // 157

  hipMemsetAsync(deg, 0, (size_t)NN * sizeof(int), stream);  // deg only

  prep_kernel<<<7509, 256, 0, stream>>>(Wq, Wk, Wv, Wt, x, gamma, beta, Xn, ei, deg, rank);
  scan_part<<<157, 256, 0, stream>>>(deg, base, bsum);
  scan_fin<<<157, 256, 0, stream>>>(base, bsum);
  qkvs_kernel<<<5625 + 2500, 256, 0, stream>>>(Xn, bq, bk, bv, Wt, Q, KV,
                                               ei, ev, m1, m2, base, rank, esl);
  agg_kernel<<<NN / 4, 256, 0, stream>>>(x, Q, KV, esl, base, out);
}